// Round 5
// baseline (165.878 us; speedup 1.0000x reference)
//
#include <hip/hip_runtime.h>
#include <hip/hip_bf16.h>

#define N_PITCH 576
#define D_MODEL 128

// Prep: WT[p*128 + d] = W[d*577 + p] + b[d]   for p in [0,576)
//       WT[576*128 + d] = W[d*577 + 576]      (gain weight, no bias)
__global__ void prep_kernel(const float* __restrict__ W,
                            const float* __restrict__ b,
                            float* __restrict__ WT) {
    int i = blockIdx.x * blockDim.x + threadIdx.x;
    const int total = (N_PITCH + 1) * D_MODEL;
    if (i < total) {
        int p = i >> 7;        // / 128
        int d = i & 127;       // % 128
        float v = W[d * (N_PITCH + 1) + p];
        if (p < N_PITCH) v += b[d];
        WT[i] = v;
    }
}

// Hot kernel: one 32-lane group per token; lane handles one float4 (4 of 128 dims).
// Writes are nontemporal: out (128 MiB) has zero reuse and would otherwise
// churn L2 and evict the 295 KB WT table.
__global__ void __launch_bounds__(256)
encode_kernel(const int* __restrict__ pitch,
              const float* __restrict__ gain,
              const float* __restrict__ WT,
              float* __restrict__ out,
              int ntok) {
    const float4* __restrict__ WT4 = (const float4*)WT;             // [577][32]
    const float4* __restrict__ WG4 = WT4 + N_PITCH * (D_MODEL / 4); // gain row
    float4* __restrict__ out4 = (float4*)out;

    int lane = threadIdx.x & 31;
    int grp  = (blockIdx.x * blockDim.x + threadIdx.x) >> 5;
    int ngrp = (gridDim.x * blockDim.x) >> 5;

    float4 wg = WG4[lane];  // loop-invariant

    for (int j = grp; j < ntok; j += ngrp) {
        int   p = __builtin_nontemporal_load(&pitch[j]);  // broadcast within group
        float g = __builtin_nontemporal_load(&gain[j]);
        float4 w = WT4[p * (D_MODEL / 4) + lane];         // L2-resident gather
        float4 r;
        r.x = fmaf(g, wg.x, w.x);
        r.y = fmaf(g, wg.y, w.y);
        r.z = fmaf(g, wg.z, w.z);
        r.w = fmaf(g, wg.w, w.w);
        float* dst = (float*)&out4[j * (D_MODEL / 4) + lane];
        __builtin_nontemporal_store(r.x, dst + 0);
        __builtin_nontemporal_store(r.y, dst + 1);
        __builtin_nontemporal_store(r.z, dst + 2);
        __builtin_nontemporal_store(r.w, dst + 3);
    }
}

extern "C" void kernel_launch(void* const* d_in, const int* in_sizes, int n_in,
                              void* d_out, int out_size, void* d_ws, size_t ws_size,
                              hipStream_t stream) {
    const int*   pitch = (const int*)d_in[0];
    const float* gain  = (const float*)d_in[1];
    const float* W     = (const float*)d_in[2];
    const float* b     = (const float*)d_in[3];
    float* out = (float*)d_out;
    float* WT  = (float*)d_ws;   // (577)*128 floats = 295,424 B

    int ntok = in_sizes[0];      // B*S = 262144

    const int prep_total = (N_PITCH + 1) * D_MODEL;
    prep_kernel<<<(prep_total + 255) / 256, 256, 0, stream>>>(W, b, WT);

    int blocks = 2048;           // grid-stride: 16 tokens per 32-lane group
    encode_kernel<<<blocks, 256, 0, stream>>>(pitch, gain, WT, out, ntok);
}

// Round 8
// 160.629 us; speedup vs baseline: 1.0327x; 1.0327x over previous
//
#include <hip/hip_runtime.h>
#include <hip/hip_bf16.h>

#define N_PITCH 576
#define D_MODEL 128

typedef __attribute__((ext_vector_type(4))) float f32x4;

// Prep: WT[p*128 + d] = W[d*577 + p] + b[d]   for p in [0,576)
//       WT[576*128 + d] = W[d*577 + 576]      (gain weight, no bias)
__global__ void prep_kernel(const float* __restrict__ W,
                            const float* __restrict__ b,
                            float* __restrict__ WT) {
    int i = blockIdx.x * blockDim.x + threadIdx.x;
    const int total = (N_PITCH + 1) * D_MODEL;
    if (i < total) {
        int p = i >> 7;        // / 128
        int d = i & 127;       // % 128
        float v = W[d * (N_PITCH + 1) + p];
        if (p < N_PITCH) v += b[d];
        WT[i] = v;
    }
}

// Hot kernel: one 32-lane group per token; lane handles one float4 (4 of 128 dims).
// Single 16B nontemporal store per lane per token (global_store_dwordx4 nt):
// out (128 MiB) has zero reuse, nt skips L2 write-allocate churn.
__global__ void __launch_bounds__(256)
encode_kernel(const int* __restrict__ pitch,
              const float* __restrict__ gain,
              const float* __restrict__ WT,
              float* __restrict__ out,
              int ntok) {
    const f32x4* __restrict__ WT4 = (const f32x4*)WT;               // [577][32]
    const f32x4* __restrict__ WG4 = WT4 + N_PITCH * (D_MODEL / 4);  // gain row
    f32x4* __restrict__ out4 = (f32x4*)out;

    int lane = threadIdx.x & 31;
    int grp  = (blockIdx.x * blockDim.x + threadIdx.x) >> 5;
    int ngrp = (gridDim.x * blockDim.x) >> 5;

    f32x4 wg = WG4[lane];  // loop-invariant

    for (int j = grp; j < ntok; j += ngrp) {
        int   p = pitch[j];   // broadcast within 32-lane group
        float g = gain[j];
        f32x4 w = WT4[p * (D_MODEL / 4) + lane];   // L2-resident gather
        f32x4 r;
        r.x = fmaf(g, wg.x, w.x);
        r.y = fmaf(g, wg.y, w.y);
        r.z = fmaf(g, wg.z, w.z);
        r.w = fmaf(g, wg.w, w.w);
        __builtin_nontemporal_store(r, &out4[j * (D_MODEL / 4) + lane]);
    }
}

extern "C" void kernel_launch(void* const* d_in, const int* in_sizes, int n_in,
                              void* d_out, int out_size, void* d_ws, size_t ws_size,
                              hipStream_t stream) {
    const int*   pitch = (const int*)d_in[0];
    const float* gain  = (const float*)d_in[1];
    const float* W     = (const float*)d_in[2];
    const float* b     = (const float*)d_in[3];
    float* out = (float*)d_out;
    float* WT  = (float*)d_ws;   // (577)*128 floats = 295,424 B

    int ntok = in_sizes[0];      // B*S = 262144

    const int prep_total = (N_PITCH + 1) * D_MODEL;
    prep_kernel<<<(prep_total + 255) / 256, 256, 0, stream>>>(W, b, WT);

    int blocks = 2048;           // 16384 groups; 262144 tokens -> exactly 16 iters/group
    encode_kernel<<<blocks, 256, 0, stream>>>(pitch, gain, WT, out, ntok);
}